// Round 13
// baseline (588.884 us; speedup 1.0000x reference)
//
#include <hip/hip_runtime.h>

#define DFEAT 256
#define NEG_ATT 0.2f
#define NEG_ACT 0.01f
#define BN_EPS 1e-5f

typedef short bf16x8 __attribute__((ext_vector_type(8)));
typedef float f32x4 __attribute__((ext_vector_type(4)));

struct Int3 { int a[3]; };
struct Cp3 { const void* p[3]; };
struct Vp3 { void* p[3]; };
struct WJobs { const float* src[12]; unsigned short* dst[12]; int K[12]; };

__device__ __forceinline__ float lrelu(float x, float s) { return x > 0.f ? x : s * x; }

// round-half-up bf16 convert: 2 VALU ops (vs 4 for RNE); differs from RNE only
// on exact ties. Validated R12 (absmax 0.0625 unchanged).
__device__ __forceinline__ unsigned short f2bf(float f) {
    union { float f; unsigned int u; } v; v.f = f;
    return (unsigned short)((v.u + 0x8000u) >> 16);
}
__device__ __forceinline__ float bf2f(unsigned short s) {
    union { unsigned int u; float f; } v; v.u = ((unsigned int)s) << 16;
    return v.f;
}
__device__ __forceinline__ float u_lo(unsigned u) {
    union { unsigned u; float f; } v; v.u = u << 16; return v.f;
}
__device__ __forceinline__ float u_hi(unsigned u) {
    union { unsigned u; float f; } v; v.u = u & 0xffff0000u; return v.f;
}

// ---------------- histogram of dst (all types) ----------------
__global__ __launch_bounds__(256)
void hist_all_k(Cp3 dst, Int3 E, int* __restrict__ counts_all, Int3 nodeOff) {
    int t = blockIdx.y;
    int e = blockIdx.x * 256 + threadIdx.x;
    if (e >= E.a[t]) return;
    const int* dstp = (const int*)dst.p[t];
    atomicAdd(&counts_all[nodeOff.a[t] + dstp[e]], 1);
}

// ---------------- hierarchical exclusive scan (all types) ----------------
__global__ __launch_bounds__(256)
void scan1_all_k(const int* __restrict__ counts_all, int* __restrict__ offs_all,
                 int* __restrict__ bsums_all, Int3 N, Int3 nodeOff, Int3 bOff) {
    int t = blockIdx.y;
    if (blockIdx.x * 256 >= N.a[t]) return;
    const int* counts = counts_all + nodeOff.a[t];
    int* offs = offs_all + nodeOff.a[t] + t;
    int* bsums = bsums_all + bOff.a[t];
    __shared__ int buf[256];
    int tt = threadIdx.x;
    int i = blockIdx.x * 256 + tt;
    int v = (i < N.a[t]) ? counts[i] : 0;
    buf[tt] = v;
    __syncthreads();
    for (int off = 1; off < 256; off <<= 1) {
        int x = (tt >= off) ? buf[tt - off] : 0;
        __syncthreads();
        buf[tt] += x;
        __syncthreads();
    }
    if (i < N.a[t]) offs[i] = buf[tt];            // inclusive within block
    if (tt == 255) bsums[blockIdx.x] = buf[255];
}

__global__ __launch_bounds__(256)
void scan2_all_k(int* __restrict__ bsums_all, Int3 N, Int3 bOff) {
    int t = blockIdx.x;
    int nb = (N.a[t] + 255) / 256;
    int* bsums = bsums_all + bOff.a[t];
    __shared__ int buf[256];
    __shared__ int carry_s;
    int tt = threadIdx.x;
    if (tt == 0) carry_s = 0;
    __syncthreads();
    for (int base = 0; base < nb; base += 256) {
        int i = base + tt;
        int v = (i < nb) ? bsums[i] : 0;
        buf[tt] = v;
        __syncthreads();
        for (int off = 1; off < 256; off <<= 1) {
            int x = (tt >= off) ? buf[tt - off] : 0;
            __syncthreads();
            buf[tt] += x;
            __syncthreads();
        }
        int incl = buf[tt];
        int c = carry_s;
        if (i < nb) bsums[i] = c + incl - v;
        __syncthreads();
        if (tt == 255) carry_s = c + buf[255];
        __syncthreads();
    }
}

__global__ __launch_bounds__(256)
void scan3_all_k(int* __restrict__ offs_all, const int* __restrict__ counts_all,
                 const int* __restrict__ bsums_all, Int3 N, Int3 E,
                 Int3 nodeOff, Int3 bOff) {
    int t = blockIdx.y;
    if (blockIdx.x * 256 >= N.a[t]) return;
    int* offs = offs_all + nodeOff.a[t] + t;
    const int* counts = counts_all + nodeOff.a[t];
    const int* bsums = bsums_all + bOff.a[t];
    int i = blockIdx.x * 256 + threadIdx.x;
    if (i < N.a[t]) offs[i] = offs[i] - counts[i] + bsums[blockIdx.x];
    if (i == 0) offs[N.a[t]] = E.a[t];
}

// ---------------- scatter edges into CSR (atomicSub restores counts to 0) ----------------
__global__ __launch_bounds__(256)
void scatter_all_k(Cp3 src, Cp3 dst, Int3 E, const int* __restrict__ offs_all,
                   int* __restrict__ counts_all, int* __restrict__ csr_all,
                   Int3 nodeOff, Int3 edgeOff) {
    int t = blockIdx.y;
    int e = blockIdx.x * 256 + threadIdx.x;
    if (e >= E.a[t]) return;
    const int* srcp = (const int*)src.p[t];
    const int* dstp = (const int*)dst.p[t];
    const int* offs = offs_all + nodeOff.a[t] + t;
    int* cursor = counts_all + nodeOff.a[t];
    int* csr = csr_all + edgeOff.a[t];
    int d = dstp[e];
    int pos = atomicSub(&cursor[d], 1) - 1;   // counts end back at 0
    csr[offs[d] + pos] = srcp[e];
}

// ---------------- weight transpose via LDS tiles: W[K][256] f32 -> Bt[256][K] bf16 ----------------
__global__ __launch_bounds__(256)
void wcast_tr_k(WJobs jobs) {
    int j = blockIdx.z;
    int K = jobs.K[j];
    int k0 = blockIdx.y * 64;
    if (k0 >= K) return;
    int n0 = blockIdx.x * 64;
    const float* W = jobs.src[j];
    unsigned short* Bt = jobs.dst[j];
    __shared__ float tile[64][65];
    int tid = threadIdx.x;
    int tr = tid >> 4;
    int tc4 = (tid & 15) << 2;
#pragma unroll
    for (int r = 0; r < 4; ++r) {
        int k = tr + r * 16;
        float4 v = *(const float4*)(W + (size_t)(k0 + k) * 256 + n0 + tc4);
        tile[k][tc4] = v.x; tile[k][tc4 + 1] = v.y;
        tile[k][tc4 + 2] = v.z; tile[k][tc4 + 3] = v.w;
    }
    __syncthreads();
    int n = tid >> 2;
    int kc = (tid & 3) << 4;
    unsigned o[8];
#pragma unroll
    for (int q = 0; q < 8; ++q) {
        float v0 = tile[kc + 2 * q][n];
        float v1 = tile[kc + 2 * q + 1][n];
        o[q] = (unsigned)f2bf(v0) | ((unsigned)f2bf(v1) << 16);
    }
    unsigned short* dp = Bt + (size_t)(n0 + n) * K + k0 + kc;
    *(uint4*)dp = make_uint4(o[0], o[1], o[2], o[3]);
    *(uint4*)(dp + 8) = make_uint4(o[4], o[5], o[6], o[7]);
}

// ---------------- MFMA GEMM (all types): C[M,512] bf16 = A[M,K] @ Bt[512,K]^T ----------------
// AMODE: 0 = A bf16 raw; 1 = A fp32 (cast in staging); 2 = A bf16 + fused BN(scale/shift)+lrelu
// R13: operand-swapped MFMA (bfv first) -> lane holds C-row = mw+16i+l16 and 4
// CONSECUTIVE C-cols in regs 0..3 -> epilogue = 16 packed 8B stores (was 64
// scalar 2B stores). Same dot products, numerically identical.
template<int AMODE>
__global__ __launch_bounds__(256)
void mfma_gemm_all_k(Cp3 Ap3, Cp3 Bp3, Cp3 ssP, Vp3 Cp3v, Int3 M3, int K) {
    int t = blockIdx.z;
    int M = M3.a[t];
    int bm = blockIdx.x * 128;
    if (bm >= M) return;
    const void* Ap = Ap3.p[t];
    const unsigned short* Bt = (const unsigned short*)Bp3.p[t];
    const float* ss = (const float*)ssP.p[t];
    unsigned short* C = (unsigned short*)Cp3v.p[t];
    const int LDK = 40;                       // padded LDS row stride
    __shared__ unsigned short As[128 * LDK];
    __shared__ unsigned short Bs[128 * LDK];
    int tid = threadIdx.x;
    int bn = blockIdx.y * 128;
    int wid = tid >> 6, lane = tid & 63;
    int quad = lane >> 4, l16 = lane & 15;
    int mw = (wid & 1) * 64, nw = (wid >> 1) * 64;
    f32x4 acc[4][4] = {};
    for (int k0 = 0; k0 < K; k0 += 32) {
#pragma unroll
        for (int i = 0; i < 2; ++i) {
            int c = tid + 256 * i;            // 0..511
            int row = c >> 2, ko = (c & 3) * 8;
            int ra = bm + row; if (ra >= M) ra = M - 1;
            if (AMODE == 1) {
                const float* Af = (const float*)Ap;
                float4 a0 = *(const float4*)(Af + (size_t)ra * K + k0 + ko);
                float4 a1 = *(const float4*)(Af + (size_t)ra * K + k0 + ko + 4);
                ushort4 lo, hi;
                lo.x = f2bf(a0.x); lo.y = f2bf(a0.y); lo.z = f2bf(a0.z); lo.w = f2bf(a0.w);
                hi.x = f2bf(a1.x); hi.y = f2bf(a1.y); hi.z = f2bf(a1.z); hi.w = f2bf(a1.w);
                *(ushort4*)&As[row * LDK + ko] = lo;
                *(ushort4*)&As[row * LDK + ko + 4] = hi;
            } else if (AMODE == 2) {
                const unsigned short* Ab = (const unsigned short*)Ap;
                uint4 va = *(const uint4*)(Ab + (size_t)ra * K + k0 + ko);
                const unsigned* up = (const unsigned*)&va;
                float4 sc0 = *(const float4*)(ss + k0 + ko);
                float4 sc1 = *(const float4*)(ss + k0 + ko + 4);
                float4 sh0 = *(const float4*)(ss + 256 + k0 + ko);
                float4 sh1 = *(const float4*)(ss + 256 + k0 + ko + 4);
                float fv[8] = {u_lo(up[0]), u_hi(up[0]), u_lo(up[1]), u_hi(up[1]),
                               u_lo(up[2]), u_hi(up[2]), u_lo(up[3]), u_hi(up[3])};
                float scv[8] = {sc0.x, sc0.y, sc0.z, sc0.w, sc1.x, sc1.y, sc1.z, sc1.w};
                float shv[8] = {sh0.x, sh0.y, sh0.z, sh0.w, sh1.x, sh1.y, sh1.z, sh1.w};
                unsigned ov[4];
#pragma unroll
                for (int q = 0; q < 4; ++q) {
                    float v0 = fmaf(fv[2 * q], scv[2 * q], shv[2 * q]);
                    v0 = fmaxf(v0, NEG_ACT * v0);
                    float v1 = fmaf(fv[2 * q + 1], scv[2 * q + 1], shv[2 * q + 1]);
                    v1 = fmaxf(v1, NEG_ACT * v1);
                    ov[q] = (unsigned)f2bf(v0) | ((unsigned)f2bf(v1) << 16);
                }
                *(uint4*)&As[row * LDK + ko] = make_uint4(ov[0], ov[1], ov[2], ov[3]);
            } else {
                const unsigned short* Ab = (const unsigned short*)Ap;
                uint4 va = *(const uint4*)(Ab + (size_t)ra * K + k0 + ko);
                *(uint4*)&As[row * LDK + ko] = va;
            }
            uint4 vb = *(const uint4*)(Bt + (size_t)(bn + row) * K + k0 + ko);
            *(uint4*)&Bs[row * LDK + ko] = vb;
        }
        __syncthreads();
        bf16x8 af[4], bfv[4];
#pragma unroll
        for (int i = 0; i < 4; ++i)
            af[i] = *(bf16x8*)&As[(mw + 16 * i + l16) * LDK + quad * 8];
#pragma unroll
        for (int u = 0; u < 4; ++u)
            bfv[u] = *(bf16x8*)&Bs[(nw + 16 * u + l16) * LDK + quad * 8];
#pragma unroll
        for (int i = 0; i < 4; ++i)
#pragma unroll
            for (int u = 0; u < 4; ++u)
                acc[i][u] = __builtin_amdgcn_mfma_f32_16x16x32_bf16(bfv[u], af[i], acc[i][u], 0, 0, 0);
        __syncthreads();
    }
    // epilogue: lane holds C-row = bm+mw+16i+l16; C-cols = bn+nw+16u+quad*4+reg
#pragma unroll
    for (int i = 0; i < 4; ++i) {
        int grow = bm + mw + 16 * i + l16;
        if (grow < M) {
            unsigned short* cp = C + (size_t)grow * 512 + bn + nw + quad * 4;
#pragma unroll
            for (int u = 0; u < 4; ++u) {
                unsigned lo = (unsigned)f2bf(acc[i][u][0]) | ((unsigned)f2bf(acc[i][u][1]) << 16);
                unsigned hi = (unsigned)f2bf(acc[i][u][2]) | ((unsigned)f2bf(acc[i][u][3]) << 16);
                *(uint2*)(cp + 16 * u) = make_uint2(lo, hi);
            }
        }
    }
}

// ---------------- GATv2 gather (all types): EXACT R7 structure (frozen) ----------------
// One 512B row per wave memory instruction (L2 locality, R8 lesson). Single
// predicated batch-8 loop (VGPR 32; splitting it doubled live ranges -> 60, R9 lesson).
__global__ __launch_bounds__(256)
void gat_gather_all_k(Cp3 hl3, Cp3 offs3, Cp3 csr3, Cp3 att3, Cp3 bias3,
                      Vp3 out3, Int3 N3) {
    int t = blockIdx.z;
    int N = N3.a[t];
    int wave = (blockIdx.x * 256 + threadIdx.x) >> 6;
    int lane = threadIdx.x & 63;
    if (wave >= N) return;
    const char* hlB = (const char*)hl3.p[t];        // row stride 1024 B (hl||hr)
    const int* offs = (const int*)offs3.p[t];
    const int* csr = (const int*)csr3.p[t];
    const float* att = (const float*)att3.p[t];
    const float* bias = (const float*)bias3.p[t];
    unsigned short* out = (unsigned short*)out3.p[t];
    int d = wave;
    unsigned lOff = (unsigned)lane << 3;            // 8 B = 4 bf16 channels
    ushort4 hru = *(const ushort4*)(hlB + (((unsigned)d << 10) + 512u + lOff));
    float hr0 = bf2f(hru.x), hr1 = bf2f(hru.y), hr2 = bf2f(hru.z), hr3 = bf2f(hru.w);
    float4 av  = *(const float4*)(att + (lane << 2));
    float4 bv  = *(const float4*)(bias + (lane << 2));
    float l = 0.f, ac0 = 0.f, ac1 = 0.f, ac2 = 0.f, ac3 = 0.f;

    auto update = [&](ushort4 u) {
        float h0 = bf2f(u.x), h1 = bf2f(u.y), h2 = bf2f(u.z), h3 = bf2f(u.w);
        float x0 = h0 + hr0; x0 = fmaxf(x0, NEG_ATT * x0);   // exact leaky_relu
        float x1 = h1 + hr1; x1 = fmaxf(x1, NEG_ATT * x1);
        float x2 = h2 + hr2; x2 = fmaxf(x2, NEG_ATT * x2);
        float x3 = h3 + hr3; x3 = fmaxf(x3, NEG_ATT * x3);
        float part = x0 * av.x;
        part = fmaf(x1, av.y, part);
        part = fmaf(x2, av.z, part);
        part = fmaf(x3, av.w, part);
        part += __shfl_xor(part, 1);
        part += __shfl_xor(part, 2);
        part += __shfl_xor(part, 4);
        part += __shfl_xor(part, 8);        // per-head score (16-lane groups)
        float p = __expf(part);             // |score| small: shift-free softmax safe
        l += p;
        ac0 = fmaf(p, h0, ac0); ac1 = fmaf(p, h1, ac1);
        ac2 = fmaf(p, h2, ac2); ac3 = fmaf(p, h3, ac3);
    };

    update(*(const ushort4*)(hlB + (((unsigned)d << 10) + lOff)));   // self-loop

    int beg = offs[d];
    int deg = offs[d + 1] - beg;
    for (int base = 0; base < deg; base += 64) {
        int cnt = min(64, deg - base);
        int my = (base + lane < deg) ? csr[beg + base + lane] : d;
        for (int j = 0; j < cnt; j += 8) {
            int kk = min(8, cnt - j);
            ushort4 v[8];
#pragma unroll
            for (int u = 0; u < 8; ++u) {
                int s = __shfl(my, (j + u) & 63);
                if (u < kk) v[u] = *(const ushort4*)(hlB + (((unsigned)s << 10) + lOff));
            }
#pragma unroll
            for (int u = 0; u < 8; ++u)
                if (u < kk) update(v[u]);
        }
    }
    float inv = 1.f / (l + 1e-16f);
    ushort4 o;
    o.x = f2bf(fmaf(ac0, inv, bv.x));
    o.y = f2bf(fmaf(ac1, inv, bv.y));
    o.z = f2bf(fmaf(ac2, inv, bv.z));
    o.w = f2bf(fmaf(ac3, inv, bv.w));
    *(ushort4*)((char*)out + (((unsigned)d << 9) + lOff)) = o;
}

// ---------------- BN stats (all types): vectorized ushort8 loads ----------------
__global__ __launch_bounds__(256)
void bn_stats_all_k(Cp3 h3, Vp3 st3, Int3 N3) {
    int t = blockIdx.y;
    const unsigned short* hp = (const unsigned short*)h3.p[t];
    float* st = (float*)st3.p[t];
    long total = (long)N3.a[t] * 256;
    int tid = threadIdx.x;
    long gt = (long)blockIdx.x * 256 + tid;
    long stride = (long)gridDim.x * 256 * 8;
    float s[8] = {0.f}, s2[8] = {0.f};
    for (long p = gt * 8; p < total; p += stride) {
        uint4 u = *(const uint4*)(hp + p);
        unsigned short* us = (unsigned short*)&u;   // 8 bf16
#pragma unroll
        for (int j = 0; j < 8; ++j) { float v = bf2f(us[j]); s[j] += v; s2[j] += v * v; }
    }
#pragma unroll
    for (int j = 0; j < 8; ++j) { s[j] += __shfl_xor(s[j], 32); s2[j] += __shfl_xor(s2[j], 32); }
    __shared__ float lds[2048];
    int wv = tid >> 6, lane = tid & 63;
    if (lane < 32) {
#pragma unroll
        for (int j = 0; j < 8; ++j) {
            lds[wv * 512 + lane * 8 + j] = s[j];
            lds[wv * 512 + 256 + lane * 8 + j] = s2[j];
        }
    }
    __syncthreads();
    for (int q = tid; q < 512; q += 256) {
        float v = lds[q] + lds[512 + q] + lds[1024 + q] + lds[1536 + q];
        atomicAdd(&st[q], v);
    }
}

// ---------------- BN finalize: stats -> per-feature (scale, shift) ----------------
__global__ __launch_bounds__(256)
void bn_finalize_all_k(Cp3 st3, const float* __restrict__ gb, const float* __restrict__ bb,
                       Vp3 ss3, Int3 N3) {
    int t = blockIdx.x;
    const float* st = (const float*)st3.p[t];
    float* ss = (float*)ss3.p[t];
    int f = threadIdx.x;
    float invN = 1.f / (float)N3.a[t];
    float mu  = st[f] * invN;
    float var = st[256 + f] * invN - mu * mu;
    float sc  = gb[t * DFEAT + f] / sqrtf(var + BN_EPS);
    ss[f] = sc;
    ss[256 + f] = bb[t * DFEAT + f] - mu * sc;
}

// ---------------- fused BN + leaky_relu + classifier (all types) ----------------
__global__ __launch_bounds__(256)
void bn_cls_all_k(Cp3 R3, Cp3 st3, const float* __restrict__ gb, const float* __restrict__ bb,
                  const float* __restrict__ cW, const float* __restrict__ cb,
                  Vp3 out3, Int3 N3) {
    int t = blockIdx.y;
    int N = N3.a[t];
    int wave = (blockIdx.x * 256 + threadIdx.x) >> 6;
    int lane = threadIdx.x & 63;
    if (wave >= N) return;
    const unsigned short* R = (const unsigned short*)R3.p[t];
    const float* stats = (const float*)st3.p[t];
    const float* g = gb + (size_t)t * DFEAT;
    const float* b = bb + (size_t)t * DFEAT;
    float* out = (float*)out3.p[t];
    int f4 = lane << 2;
    float invN = 1.f / (float)N;
    ushort4 u = *(const ushort4*)(R + (size_t)wave * DFEAT + f4);
    float vv[4] = {bf2f(u.x), bf2f(u.y), bf2f(u.z), bf2f(u.w)};
    float p0 = 0.f, p1 = 0.f;
#pragma unroll
    for (int j = 0; j < 4; ++j) {
        int f = f4 + j;
        float mu  = stats[f] * invN;
        float var = stats[DFEAT + f] * invN - mu * mu;
        float sc  = g[f] / sqrtf(var + BN_EPS);
        float val = lrelu((vv[j] - mu) * sc + b[f], NEG_ACT);
        float2 w = *(const float2*)(cW + (size_t)f * 2);
        p0 += val * w.x;
        p1 += val * w.y;
    }
#pragma unroll
    for (int off = 1; off < 64; off <<= 1) {
        p0 += __shfl_xor(p0, off);
        p1 += __shfl_xor(p1, off);
    }
    if (lane == 0) {
        out[(size_t)wave * 2 + 0] = p0 + cb[0];
        out[(size_t)wave * 2 + 1] = p1 + cb[1];
    }
}

extern "C" void kernel_launch(void* const* d_in, const int* in_sizes, int n_in,
                              void* d_out, int out_size, void* d_ws, size_t ws_size,
                              hipStream_t stream) {
    const float* x0 = (const float*)d_in[0];
    const float* x1 = (const float*)d_in[1];
    const float* x2 = (const float*)d_in[2];
    const int* ei[3] = {(const int*)d_in[3], (const int*)d_in[4], (const int*)d_in[5]};
    const float* Wl1 = (const float*)d_in[6];
    const float* Wr1 = (const float*)d_in[7];
    const float* att1 = (const float*)d_in[8];
    const float* b1 = (const float*)d_in[9];
    const float* Wl2 = (const float*)d_in[10];
    const float* Wr2 = (const float*)d_in[11];
    const float* att2 = (const float*)d_in[12];
    const float* b2 = (const float*)d_in[13];
    const float* bn_g = (const float*)d_in[14];
    const float* bn_b = (const float*)d_in[15];
    const float* cW = (const float*)d_in[16];
    const float* cb = (const float*)d_in[17];

    Int3 N3, E3, nodeOff, edgeOff, bOff;
    N3.a[0] = in_sizes[0] / 128; N3.a[1] = in_sizes[1] / 128; N3.a[2] = in_sizes[2] / 128;
    E3.a[0] = in_sizes[3] / 2;   E3.a[1] = in_sizes[4] / 2;   E3.a[2] = in_sizes[5] / 2;
    int Ntot = 0, Etot = 0, btot = 0;
    int maxN = 0, maxE = 0;
    for (int i = 0; i < 3; ++i) {
        nodeOff.a[i] = Ntot; edgeOff.a[i] = Etot; bOff.a[i] = btot;
        Ntot += N3.a[i]; Etot += E3.a[i]; btot += (N3.a[i] + 255) / 256;
        if (N3.a[i] > maxN) maxN = N3.a[i];
        if (E3.a[i] > maxE) maxE = E3.a[i];
    }

    char* w = (char*)d_ws;
    auto alloc_b = [&](size_t bytes) -> void* {
        void* p = (void*)w;
        w += (bytes + 255) & ~(size_t)255;
        return p;
    };
    unsigned short* C_all  = (unsigned short*)alloc_b((size_t)Ntot * 512 * sizeof(unsigned short));
    unsigned short* Rb_all = (unsigned short*)alloc_b((size_t)Ntot * DFEAT * sizeof(unsigned short));
    unsigned short* Bt1 = (unsigned short*)alloc_b((size_t)3 * 512 * 128 * sizeof(unsigned short));
    unsigned short* Bt2 = (unsigned short*)alloc_b((size_t)3 * 512 * 256 * sizeof(unsigned short));
    // counts_all and stats_all adjacent -> single memset covers both
    int* counts_all = (int*)alloc_b((size_t)Ntot * sizeof(int));
    float* stats_all = (float*)alloc_b((size_t)6 * 512 * sizeof(float));
    int* offs_all   = (int*)alloc_b((size_t)(Ntot + 3) * sizeof(int));
    int* csr_all    = (int*)alloc_b((size_t)Etot * sizeof(int));
    int* bsums_all  = (int*)alloc_b((size_t)btot * sizeof(int));
    float* ss_all    = (float*)alloc_b((size_t)3 * 512 * sizeof(float));
    size_t zero_bytes = (size_t)((char*)(stats_all + 6 * 512) - (char*)counts_all);

    // per-type pointer packs
    Cp3 srcP, dstP, xP, Bt1P, Bt2P, hlP, offsP, csrP, att1P, att2P, b1P, b2P;
    Cp3 RbCP, st1CP, st2CP, ssCP, dumP;
    Vp3 CP, RbP, st1P, st2P, ssP, outP;
    for (int i = 0; i < 3; ++i) {
        srcP.p[i] = ei[i];
        dstP.p[i] = ei[i] + E3.a[i];
        xP.p[i] = (i == 0) ? (const void*)x0 : (i == 1) ? (const void*)x1 : (const void*)x2;
        Bt1P.p[i] = Bt1 + (size_t)i * 512 * 128;
        Bt2P.p[i] = Bt2 + (size_t)i * 512 * 256;
        CP.p[i] = C_all + (size_t)nodeOff.a[i] * 512;
        hlP.p[i] = CP.p[i];
        RbP.p[i] = Rb_all + (size_t)nodeOff.a[i] * DFEAT;
        RbCP.p[i] = RbP.p[i];
        offsP.p[i] = offs_all + nodeOff.a[i] + i;
        csrP.p[i] = csr_all + edgeOff.a[i];
        att1P.p[i] = att1 + (size_t)i * DFEAT;
        att2P.p[i] = att2 + (size_t)i * DFEAT;
        b1P.p[i] = b1 + (size_t)i * DFEAT;
        b2P.p[i] = b2 + (size_t)i * DFEAT;
        st1P.p[i] = stats_all + (size_t)i * 512;
        st2P.p[i] = stats_all + (size_t)(3 + i) * 512;
        st1CP.p[i] = st1P.p[i];
        st2CP.p[i] = st2P.p[i];
        ssP.p[i] = ss_all + (size_t)i * 512;
        ssCP.p[i] = ssP.p[i];
        dumP.p[i] = xP.p[i];
        outP.p[i] = (float*)d_out + (size_t)nodeOff.a[i] * 2;
    }

    int maxNblk = (maxN + 255) / 256;
    int maxEblk = (maxE + 255) / 256;
    int maxMtile = (maxN + 127) / 128;
    int maxNwave = (maxN + 3) / 4;

    // one-time prep
    hipMemsetAsync(counts_all, 0, zero_bytes, stream);
    {
        WJobs jobs;
        for (int i = 0; i < 3; ++i) {
            jobs.src[i * 4 + 0] = Wl1 + (size_t)i * 128 * 256;
            jobs.dst[i * 4 + 0] = (unsigned short*)Bt1P.p[i];
            jobs.K[i * 4 + 0] = 128;
            jobs.src[i * 4 + 1] = Wr1 + (size_t)i * 128 * 256;
            jobs.dst[i * 4 + 1] = (unsigned short*)Bt1P.p[i] + (size_t)256 * 128;
            jobs.K[i * 4 + 1] = 128;
            jobs.src[i * 4 + 2] = Wl2 + (size_t)i * 256 * 256;
            jobs.dst[i * 4 + 2] = (unsigned short*)Bt2P.p[i];
            jobs.K[i * 4 + 2] = 256;
            jobs.src[i * 4 + 3] = Wr2 + (size_t)i * 256 * 256;
            jobs.dst[i * 4 + 3] = (unsigned short*)Bt2P.p[i] + (size_t)256 * 256;
            jobs.K[i * 4 + 3] = 256;
        }
        wcast_tr_k<<<dim3(4, 4, 12), 256, 0, stream>>>(jobs);
    }

    // ---- CSR build (all types) ----
    hist_all_k<<<dim3(maxEblk, 3), 256, 0, stream>>>(dstP, E3, counts_all, nodeOff);
    scan1_all_k<<<dim3(maxNblk, 3), 256, 0, stream>>>(counts_all, offs_all, bsums_all, N3, nodeOff, bOff);
    scan2_all_k<<<3, 256, 0, stream>>>(bsums_all, N3, bOff);
    scan3_all_k<<<dim3(maxNblk, 3), 256, 0, stream>>>(offs_all, counts_all, bsums_all, N3, E3, nodeOff, bOff);
    scatter_all_k<<<dim3(maxEblk, 3), 256, 0, stream>>>(srcP, dstP, E3, offs_all, counts_all, csr_all, nodeOff, edgeOff);

    // ---- layer 1 (A = x fp32, cast in staging) ----
    mfma_gemm_all_k<1><<<dim3(maxMtile, 4, 3), 256, 0, stream>>>(xP, Bt1P, dumP, CP, N3, 128);
    gat_gather_all_k<<<dim3(maxNwave, 1, 3), 256, 0, stream>>>(hlP, offsP, csrP, att1P, b1P, RbP, N3);
    bn_stats_all_k<<<dim3(512, 3), 256, 0, stream>>>(RbCP, st1P, N3);
    bn_finalize_all_k<<<3, 256, 0, stream>>>(st1CP, bn_g, bn_b, ssP, N3);

    // ---- layer 2 (A = Rb raw bf16 + fused BN+lrelu in staging) ----
    mfma_gemm_all_k<2><<<dim3(maxMtile, 4, 3), 256, 0, stream>>>(RbCP, Bt2P, ssCP, CP, N3, 256);
    gat_gather_all_k<<<dim3(maxNwave, 1, 3), 256, 0, stream>>>(hlP, offsP, csrP, att2P, b2P, RbP, N3);
    bn_stats_all_k<<<dim3(512, 3), 256, 0, stream>>>(RbCP, st2P, N3);

    // ---- fused BN + lrelu + classifier ----
    bn_cls_all_k<<<dim3(maxNwave, 3), 256, 0, stream>>>(RbCP, st2CP, bn_g, bn_b, cW, cb, outP, N3);
}

// Round 15
// 554.425 us; speedup vs baseline: 1.0622x; 1.0622x over previous
//
#include <hip/hip_runtime.h>

#define DFEAT 256
#define NEG_ATT 0.2f
#define NEG_ACT 0.01f
#define BN_EPS 1e-5f

typedef short bf16x8 __attribute__((ext_vector_type(8)));
typedef float f32x4 __attribute__((ext_vector_type(4)));

struct Int3 { int a[3]; };
struct Cp3 { const void* p[3]; };
struct Vp3 { void* p[3]; };
struct WJobs { const float* src[12]; unsigned short* dst[12]; int K[12]; };

__device__ __forceinline__ float lrelu(float x, float s) { return x > 0.f ? x : s * x; }

// round-half-up bf16 convert: 2 VALU ops (vs 4 for RNE); differs from RNE only
// on exact ties. Validated R12 (absmax 0.0625 unchanged).
__device__ __forceinline__ unsigned short f2bf(float f) {
    union { float f; unsigned int u; } v; v.f = f;
    return (unsigned short)((v.u + 0x8000u) >> 16);
}
__device__ __forceinline__ float bf2f(unsigned short s) {
    union { unsigned int u; float f; } v; v.u = ((unsigned int)s) << 16;
    return v.f;
}
__device__ __forceinline__ float u_lo(unsigned u) {
    union { unsigned u; float f; } v; v.u = u << 16; return v.f;
}
__device__ __forceinline__ float u_hi(unsigned u) {
    union { unsigned u; float f; } v; v.u = u & 0xffff0000u; return v.f;
}

// ---------------- histogram of dst (all types) ----------------
__global__ __launch_bounds__(256)
void hist_all_k(Cp3 dst, Int3 E, int* __restrict__ counts_all, Int3 nodeOff) {
    int t = blockIdx.y;
    int e = blockIdx.x * 256 + threadIdx.x;
    if (e >= E.a[t]) return;
    const int* dstp = (const int*)dst.p[t];
    atomicAdd(&counts_all[nodeOff.a[t] + dstp[e]], 1);
}

// ---------------- hierarchical exclusive scan (all types) ----------------
__global__ __launch_bounds__(256)
void scan1_all_k(const int* __restrict__ counts_all, int* __restrict__ offs_all,
                 int* __restrict__ bsums_all, Int3 N, Int3 nodeOff, Int3 bOff) {
    int t = blockIdx.y;
    if (blockIdx.x * 256 >= N.a[t]) return;
    const int* counts = counts_all + nodeOff.a[t];
    int* offs = offs_all + nodeOff.a[t] + t;
    int* bsums = bsums_all + bOff.a[t];
    __shared__ int buf[256];
    int tt = threadIdx.x;
    int i = blockIdx.x * 256 + tt;
    int v = (i < N.a[t]) ? counts[i] : 0;
    buf[tt] = v;
    __syncthreads();
    for (int off = 1; off < 256; off <<= 1) {
        int x = (tt >= off) ? buf[tt - off] : 0;
        __syncthreads();
        buf[tt] += x;
        __syncthreads();
    }
    if (i < N.a[t]) offs[i] = buf[tt];            // inclusive within block
    if (tt == 255) bsums[blockIdx.x] = buf[255];
}

__global__ __launch_bounds__(256)
void scan2_all_k(int* __restrict__ bsums_all, Int3 N, Int3 bOff) {
    int t = blockIdx.x;
    int nb = (N.a[t] + 255) / 256;
    int* bsums = bsums_all + bOff.a[t];
    __shared__ int buf[256];
    __shared__ int carry_s;
    int tt = threadIdx.x;
    if (tt == 0) carry_s = 0;
    __syncthreads();
    for (int base = 0; base < nb; base += 256) {
        int i = base + tt;
        int v = (i < nb) ? bsums[i] : 0;
        buf[tt] = v;
        __syncthreads();
        for (int off = 1; off < 256; off <<= 1) {
            int x = (tt >= off) ? buf[tt - off] : 0;
            __syncthreads();
            buf[tt] += x;
            __syncthreads();
        }
        int incl = buf[tt];
        int c = carry_s;
        if (i < nb) bsums[i] = c + incl - v;
        __syncthreads();
        if (tt == 255) carry_s = c + buf[255];
        __syncthreads();
    }
}

__global__ __launch_bounds__(256)
void scan3_all_k(int* __restrict__ offs_all, const int* __restrict__ counts_all,
                 const int* __restrict__ bsums_all, Int3 N, Int3 E,
                 Int3 nodeOff, Int3 bOff) {
    int t = blockIdx.y;
    if (blockIdx.x * 256 >= N.a[t]) return;
    int* offs = offs_all + nodeOff.a[t] + t;
    const int* counts = counts_all + nodeOff.a[t];
    const int* bsums = bsums_all + bOff.a[t];
    int i = blockIdx.x * 256 + threadIdx.x;
    if (i < N.a[t]) offs[i] = offs[i] - counts[i] + bsums[blockIdx.x];
    if (i == 0) offs[N.a[t]] = E.a[t];
}

// ---------------- scatter edges into CSR (atomicSub restores counts to 0) ----------------
__global__ __launch_bounds__(256)
void scatter_all_k(Cp3 src, Cp3 dst, Int3 E, const int* __restrict__ offs_all,
                   int* __restrict__ counts_all, int* __restrict__ csr_all,
                   Int3 nodeOff, Int3 edgeOff) {
    int t = blockIdx.y;
    int e = blockIdx.x * 256 + threadIdx.x;
    if (e >= E.a[t]) return;
    const int* srcp = (const int*)src.p[t];
    const int* dstp = (const int*)dst.p[t];
    const int* offs = offs_all + nodeOff.a[t] + t;
    int* cursor = counts_all + nodeOff.a[t];
    int* csr = csr_all + edgeOff.a[t];
    int d = dstp[e];
    int pos = atomicSub(&cursor[d], 1) - 1;   // counts end back at 0
    csr[offs[d] + pos] = srcp[e];
}

// ---------------- weight transpose via LDS tiles: W[K][256] f32 -> Bt[256][K] bf16 ----------------
__global__ __launch_bounds__(256)
void wcast_tr_k(WJobs jobs) {
    int j = blockIdx.z;
    int K = jobs.K[j];
    int k0 = blockIdx.y * 64;
    if (k0 >= K) return;
    int n0 = blockIdx.x * 64;
    const float* W = jobs.src[j];
    unsigned short* Bt = jobs.dst[j];
    __shared__ float tile[64][65];
    int tid = threadIdx.x;
    int tr = tid >> 4;
    int tc4 = (tid & 15) << 2;
#pragma unroll
    for (int r = 0; r < 4; ++r) {
        int k = tr + r * 16;
        float4 v = *(const float4*)(W + (size_t)(k0 + k) * 256 + n0 + tc4);
        tile[k][tc4] = v.x; tile[k][tc4 + 1] = v.y;
        tile[k][tc4 + 2] = v.z; tile[k][tc4 + 3] = v.w;
    }
    __syncthreads();
    int n = tid >> 2;
    int kc = (tid & 3) << 4;
    unsigned o[8];
#pragma unroll
    for (int q = 0; q < 8; ++q) {
        float v0 = tile[kc + 2 * q][n];
        float v1 = tile[kc + 2 * q + 1][n];
        o[q] = (unsigned)f2bf(v0) | ((unsigned)f2bf(v1) << 16);
    }
    unsigned short* dp = Bt + (size_t)(n0 + n) * K + k0 + kc;
    *(uint4*)dp = make_uint4(o[0], o[1], o[2], o[3]);
    *(uint4*)(dp + 8) = make_uint4(o[4], o[5], o[6], o[7]);
}

// ---------------- MFMA GEMM (all types): C[M,512] bf16 = A[M,K] @ Bt[512,K]^T ----------------
// AMODE: 0 = A bf16 raw; 1 = A fp32 (cast in staging); 2 = A bf16 + fused BN(scale/shift)+lrelu
template<int AMODE>
__global__ __launch_bounds__(256)
void mfma_gemm_all_k(Cp3 Ap3, Cp3 Bp3, Cp3 ssP, Vp3 Cp3v, Int3 M3, int K) {
    int t = blockIdx.z;
    int M = M3.a[t];
    int bm = blockIdx.x * 128;
    if (bm >= M) return;
    const void* Ap = Ap3.p[t];
    const unsigned short* Bt = (const unsigned short*)Bp3.p[t];
    const float* ss = (const float*)ssP.p[t];
    unsigned short* C = (unsigned short*)Cp3v.p[t];
    const int LDK = 40;                       // padded LDS row stride
    __shared__ unsigned short As[128 * LDK];
    __shared__ unsigned short Bs[128 * LDK];
    int tid = threadIdx.x;
    int bn = blockIdx.y * 128;
    int wid = tid >> 6, lane = tid & 63;
    int quad = lane >> 4, l16 = lane & 15;
    int mw = (wid & 1) * 64, nw = (wid >> 1) * 64;
    f32x4 acc[4][4] = {};
    for (int k0 = 0; k0 < K; k0 += 32) {
#pragma unroll
        for (int i = 0; i < 2; ++i) {
            int c = tid + 256 * i;            // 0..511
            int row = c >> 2, ko = (c & 3) * 8;
            int ra = bm + row; if (ra >= M) ra = M - 1;
            if (AMODE == 1) {
                const float* Af = (const float*)Ap;
                float4 a0 = *(const float4*)(Af + (size_t)ra * K + k0 + ko);
                float4 a1 = *(const float4*)(Af + (size_t)ra * K + k0 + ko + 4);
                ushort4 lo, hi;
                lo.x = f2bf(a0.x); lo.y = f2bf(a0.y); lo.z = f2bf(a0.z); lo.w = f2bf(a0.w);
                hi.x = f2bf(a1.x); hi.y = f2bf(a1.y); hi.z = f2bf(a1.z); hi.w = f2bf(a1.w);
                *(ushort4*)&As[row * LDK + ko] = lo;
                *(ushort4*)&As[row * LDK + ko + 4] = hi;
            } else if (AMODE == 2) {
                const unsigned short* Ab = (const unsigned short*)Ap;
                uint4 va = *(const uint4*)(Ab + (size_t)ra * K + k0 + ko);
                const unsigned* up = (const unsigned*)&va;
                float4 sc0 = *(const float4*)(ss + k0 + ko);
                float4 sc1 = *(const float4*)(ss + k0 + ko + 4);
                float4 sh0 = *(const float4*)(ss + 256 + k0 + ko);
                float4 sh1 = *(const float4*)(ss + 256 + k0 + ko + 4);
                float fv[8] = {u_lo(up[0]), u_hi(up[0]), u_lo(up[1]), u_hi(up[1]),
                               u_lo(up[2]), u_hi(up[2]), u_lo(up[3]), u_hi(up[3])};
                float scv[8] = {sc0.x, sc0.y, sc0.z, sc0.w, sc1.x, sc1.y, sc1.z, sc1.w};
                float shv[8] = {sh0.x, sh0.y, sh0.z, sh0.w, sh1.x, sh1.y, sh1.z, sh1.w};
                unsigned ov[4];
#pragma unroll
                for (int q = 0; q < 4; ++q) {
                    float v0 = fmaf(fv[2 * q], scv[2 * q], shv[2 * q]);
                    v0 = fmaxf(v0, NEG_ACT * v0);
                    float v1 = fmaf(fv[2 * q + 1], scv[2 * q + 1], shv[2 * q + 1]);
                    v1 = fmaxf(v1, NEG_ACT * v1);
                    ov[q] = (unsigned)f2bf(v0) | ((unsigned)f2bf(v1) << 16);
                }
                *(uint4*)&As[row * LDK + ko] = make_uint4(ov[0], ov[1], ov[2], ov[3]);
            } else {
                const unsigned short* Ab = (const unsigned short*)Ap;
                uint4 va = *(const uint4*)(Ab + (size_t)ra * K + k0 + ko);
                *(uint4*)&As[row * LDK + ko] = va;
            }
            uint4 vb = *(const uint4*)(Bt + (size_t)(bn + row) * K + k0 + ko);
            *(uint4*)&Bs[row * LDK + ko] = vb;
        }
        __syncthreads();
        bf16x8 af[4], bfv[4];
#pragma unroll
        for (int i = 0; i < 4; ++i)
            af[i] = *(bf16x8*)&As[(mw + 16 * i + l16) * LDK + quad * 8];
#pragma unroll
        for (int u = 0; u < 4; ++u)
            bfv[u] = *(bf16x8*)&Bs[(nw + 16 * u + l16) * LDK + quad * 8];
#pragma unroll
        for (int i = 0; i < 4; ++i)
#pragma unroll
            for (int u = 0; u < 4; ++u)
                acc[i][u] = __builtin_amdgcn_mfma_f32_16x16x32_bf16(af[i], bfv[u], acc[i][u], 0, 0, 0);
        __syncthreads();
    }
#pragma unroll
    for (int i = 0; i < 4; ++i) {
#pragma unroll
        for (int r = 0; r < 4; ++r) {
            int grow = bm + mw + 16 * i + quad * 4 + r;
            if (grow < M) {
#pragma unroll
                for (int u = 0; u < 4; ++u) {
                    int gcol = bn + nw + 16 * u + l16;
                    C[(size_t)grow * 512 + gcol] = f2bf(acc[i][u][r]);
                }
            }
        }
    }
}

// ---------------- GATv2 gather (all types): EXACT R7 structure (frozen) ----------------
// One 512B row per wave memory instruction (L2 locality, R8 lesson). Single
// predicated batch-8 loop (VGPR 32; splitting it doubled live ranges -> 60, R9 lesson).
__global__ __launch_bounds__(256)
void gat_gather_all_k(Cp3 hl3, Cp3 offs3, Cp3 csr3, Cp3 att3, Cp3 bias3,
                      Vp3 out3, Int3 N3) {
    int t = blockIdx.z;
    int N = N3.a[t];
    int wave = (blockIdx.x * 256 + threadIdx.x) >> 6;
    int lane = threadIdx.x & 63;
    if (wave >= N) return;
    const char* hlB = (const char*)hl3.p[t];        // row stride 1024 B (hl||hr)
    const int* offs = (const int*)offs3.p[t];
    const int* csr = (const int*)csr3.p[t];
    const float* att = (const float*)att3.p[t];
    const float* bias = (const float*)bias3.p[t];
    unsigned short* out = (unsigned short*)out3.p[t];
    int d = wave;
    unsigned lOff = (unsigned)lane << 3;            // 8 B = 4 bf16 channels
    ushort4 hru = *(const ushort4*)(hlB + (((unsigned)d << 10) + 512u + lOff));
    float hr0 = bf2f(hru.x), hr1 = bf2f(hru.y), hr2 = bf2f(hru.z), hr3 = bf2f(hru.w);
    float4 av  = *(const float4*)(att + (lane << 2));
    float4 bv  = *(const float4*)(bias + (lane << 2));
    float l = 0.f, ac0 = 0.f, ac1 = 0.f, ac2 = 0.f, ac3 = 0.f;

    auto update = [&](ushort4 u) {
        float h0 = bf2f(u.x), h1 = bf2f(u.y), h2 = bf2f(u.z), h3 = bf2f(u.w);
        float x0 = h0 + hr0; x0 = fmaxf(x0, NEG_ATT * x0);   // exact leaky_relu
        float x1 = h1 + hr1; x1 = fmaxf(x1, NEG_ATT * x1);
        float x2 = h2 + hr2; x2 = fmaxf(x2, NEG_ATT * x2);
        float x3 = h3 + hr3; x3 = fmaxf(x3, NEG_ATT * x3);
        float part = x0 * av.x;
        part = fmaf(x1, av.y, part);
        part = fmaf(x2, av.z, part);
        part = fmaf(x3, av.w, part);
        part += __shfl_xor(part, 1);
        part += __shfl_xor(part, 2);
        part += __shfl_xor(part, 4);
        part += __shfl_xor(part, 8);        // per-head score (16-lane groups)
        float p = __expf(part);             // |score| small: shift-free softmax safe
        l += p;
        ac0 = fmaf(p, h0, ac0); ac1 = fmaf(p, h1, ac1);
        ac2 = fmaf(p, h2, ac2); ac3 = fmaf(p, h3, ac3);
    };

    update(*(const ushort4*)(hlB + (((unsigned)d << 10) + lOff)));   // self-loop

    int beg = offs[d];
    int deg = offs[d + 1] - beg;
    for (int base = 0; base < deg; base += 64) {
        int cnt = min(64, deg - base);
        int my = (base + lane < deg) ? csr[beg + base + lane] : d;
        for (int j = 0; j < cnt; j += 8) {
            int kk = min(8, cnt - j);
            ushort4 v[8];
#pragma unroll
            for (int u = 0; u < 8; ++u) {
                int s = __shfl(my, (j + u) & 63);
                if (u < kk) v[u] = *(const ushort4*)(hlB + (((unsigned)s << 10) + lOff));
            }
#pragma unroll
            for (int u = 0; u < 8; ++u)
                if (u < kk) update(v[u]);
        }
    }
    float inv = 1.f / (l + 1e-16f);
    ushort4 o;
    o.x = f2bf(fmaf(ac0, inv, bv.x));
    o.y = f2bf(fmaf(ac1, inv, bv.y));
    o.z = f2bf(fmaf(ac2, inv, bv.z));
    o.w = f2bf(fmaf(ac3, inv, bv.w));
    *(ushort4*)((char*)out + (((unsigned)d << 9) + lOff)) = o;
}

// ---------------- BN stats (all types): vectorized ushort8 loads ----------------
__global__ __launch_bounds__(256)
void bn_stats_all_k(Cp3 h3, Vp3 st3, Int3 N3) {
    int t = blockIdx.y;
    const unsigned short* hp = (const unsigned short*)h3.p[t];
    float* st = (float*)st3.p[t];
    long total = (long)N3.a[t] * 256;
    int tid = threadIdx.x;
    long gt = (long)blockIdx.x * 256 + tid;
    long stride = (long)gridDim.x * 256 * 8;
    float s[8] = {0.f}, s2[8] = {0.f};
    for (long p = gt * 8; p < total; p += stride) {
        uint4 u = *(const uint4*)(hp + p);
        unsigned short* us = (unsigned short*)&u;   // 8 bf16
#pragma unroll
        for (int j = 0; j < 8; ++j) { float v = bf2f(us[j]); s[j] += v; s2[j] += v * v; }
    }
#pragma unroll
    for (int j = 0; j < 8; ++j) { s[j] += __shfl_xor(s[j], 32); s2[j] += __shfl_xor(s2[j], 32); }
    __shared__ float lds[2048];
    int wv = tid >> 6, lane = tid & 63;
    if (lane < 32) {
#pragma unroll
        for (int j = 0; j < 8; ++j) {
            lds[wv * 512 + lane * 8 + j] = s[j];
            lds[wv * 512 + 256 + lane * 8 + j] = s2[j];
        }
    }
    __syncthreads();
    for (int q = tid; q < 512; q += 256) {
        float v = lds[q] + lds[512 + q] + lds[1024 + q] + lds[1536 + q];
        atomicAdd(&st[q], v);
    }
}

// ---------------- BN finalize: stats -> per-feature (scale, shift) ----------------
__global__ __launch_bounds__(256)
void bn_finalize_all_k(Cp3 st3, const float* __restrict__ gb, const float* __restrict__ bb,
                       Vp3 ss3, Int3 N3) {
    int t = blockIdx.x;
    const float* st = (const float*)st3.p[t];
    float* ss = (float*)ss3.p[t];
    int f = threadIdx.x;
    float invN = 1.f / (float)N3.a[t];
    float mu  = st[f] * invN;
    float var = st[256 + f] * invN - mu * mu;
    float sc  = gb[t * DFEAT + f] / sqrtf(var + BN_EPS);
    ss[f] = sc;
    ss[256 + f] = bb[t * DFEAT + f] - mu * sc;
}

// ---------------- fused BN + leaky_relu + classifier (all types) ----------------
__global__ __launch_bounds__(256)
void bn_cls_all_k(Cp3 R3, Cp3 st3, const float* __restrict__ gb, const float* __restrict__ bb,
                  const float* __restrict__ cW, const float* __restrict__ cb,
                  Vp3 out3, Int3 N3) {
    int t = blockIdx.y;
    int N = N3.a[t];
    int wave = (blockIdx.x * 256 + threadIdx.x) >> 6;
    int lane = threadIdx.x & 63;
    if (wave >= N) return;
    const unsigned short* R = (const unsigned short*)R3.p[t];
    const float* stats = (const float*)st3.p[t];
    const float* g = gb + (size_t)t * DFEAT;
    const float* b = bb + (size_t)t * DFEAT;
    float* out = (float*)out3.p[t];
    int f4 = lane << 2;
    float invN = 1.f / (float)N;
    ushort4 u = *(const ushort4*)(R + (size_t)wave * DFEAT + f4);
    float vv[4] = {bf2f(u.x), bf2f(u.y), bf2f(u.z), bf2f(u.w)};
    float p0 = 0.f, p1 = 0.f;
#pragma unroll
    for (int j = 0; j < 4; ++j) {
        int f = f4 + j;
        float mu  = stats[f] * invN;
        float var = stats[DFEAT + f] * invN - mu * mu;
        float sc  = g[f] / sqrtf(var + BN_EPS);
        float val = lrelu((vv[j] - mu) * sc + b[f], NEG_ACT);
        float2 w = *(const float2*)(cW + (size_t)f * 2);
        p0 += val * w.x;
        p1 += val * w.y;
    }
#pragma unroll
    for (int off = 1; off < 64; off <<= 1) {
        p0 += __shfl_xor(p0, off);
        p1 += __shfl_xor(p1, off);
    }
    if (lane == 0) {
        out[(size_t)wave * 2 + 0] = p0 + cb[0];
        out[(size_t)wave * 2 + 1] = p1 + cb[1];
    }
}

extern "C" void kernel_launch(void* const* d_in, const int* in_sizes, int n_in,
                              void* d_out, int out_size, void* d_ws, size_t ws_size,
                              hipStream_t stream) {
    const float* x0 = (const float*)d_in[0];
    const float* x1 = (const float*)d_in[1];
    const float* x2 = (const float*)d_in[2];
    const int* ei[3] = {(const int*)d_in[3], (const int*)d_in[4], (const int*)d_in[5]};
    const float* Wl1 = (const float*)d_in[6];
    const float* Wr1 = (const float*)d_in[7];
    const float* att1 = (const float*)d_in[8];
    const float* b1 = (const float*)d_in[9];
    const float* Wl2 = (const float*)d_in[10];
    const float* Wr2 = (const float*)d_in[11];
    const float* att2 = (const float*)d_in[12];
    const float* b2 = (const float*)d_in[13];
    const float* bn_g = (const float*)d_in[14];
    const float* bn_b = (const float*)d_in[15];
    const float* cW = (const float*)d_in[16];
    const float* cb = (const float*)d_in[17];

    Int3 N3, E3, nodeOff, edgeOff, bOff;
    N3.a[0] = in_sizes[0] / 128; N3.a[1] = in_sizes[1] / 128; N3.a[2] = in_sizes[2] / 128;
    E3.a[0] = in_sizes[3] / 2;   E3.a[1] = in_sizes[4] / 2;   E3.a[2] = in_sizes[5] / 2;
    int Ntot = 0, Etot = 0, btot = 0;
    int maxN = 0, maxE = 0;
    for (int i = 0; i < 3; ++i) {
        nodeOff.a[i] = Ntot; edgeOff.a[i] = Etot; bOff.a[i] = btot;
        Ntot += N3.a[i]; Etot += E3.a[i]; btot += (N3.a[i] + 255) / 256;
        if (N3.a[i] > maxN) maxN = N3.a[i];
        if (E3.a[i] > maxE) maxE = E3.a[i];
    }

    char* w = (char*)d_ws;
    auto alloc_b = [&](size_t bytes) -> void* {
        void* p = (void*)w;
        w += (bytes + 255) & ~(size_t)255;
        return p;
    };
    unsigned short* C_all  = (unsigned short*)alloc_b((size_t)Ntot * 512 * sizeof(unsigned short));
    unsigned short* Rb_all = (unsigned short*)alloc_b((size_t)Ntot * DFEAT * sizeof(unsigned short));
    unsigned short* Bt1 = (unsigned short*)alloc_b((size_t)3 * 512 * 128 * sizeof(unsigned short));
    unsigned short* Bt2 = (unsigned short*)alloc_b((size_t)3 * 512 * 256 * sizeof(unsigned short));
    int* counts_all = (int*)alloc_b((size_t)Ntot * sizeof(int));
    int* offs_all   = (int*)alloc_b((size_t)(Ntot + 3) * sizeof(int));
    int* csr_all    = (int*)alloc_b((size_t)Etot * sizeof(int));
    int* bsums_all  = (int*)alloc_b((size_t)btot * sizeof(int));
    float* stats_all = (float*)alloc_b((size_t)6 * 512 * sizeof(float));
    float* ss_all    = (float*)alloc_b((size_t)3 * 512 * sizeof(float));

    // per-type pointer packs
    Cp3 srcP, dstP, xP, Bt1P, Bt2P, hlP, offsP, csrP, att1P, att2P, b1P, b2P;
    Cp3 RbCP, st1CP, st2CP, ssCP, dumP;
    Vp3 CP, RbP, st1P, st2P, ssP, outP;
    for (int i = 0; i < 3; ++i) {
        srcP.p[i] = ei[i];
        dstP.p[i] = ei[i] + E3.a[i];
        xP.p[i] = (i == 0) ? (const void*)x0 : (i == 1) ? (const void*)x1 : (const void*)x2;
        Bt1P.p[i] = Bt1 + (size_t)i * 512 * 128;
        Bt2P.p[i] = Bt2 + (size_t)i * 512 * 256;
        CP.p[i] = C_all + (size_t)nodeOff.a[i] * 512;
        hlP.p[i] = CP.p[i];
        RbP.p[i] = Rb_all + (size_t)nodeOff.a[i] * DFEAT;
        RbCP.p[i] = RbP.p[i];
        offsP.p[i] = offs_all + nodeOff.a[i] + i;
        csrP.p[i] = csr_all + edgeOff.a[i];
        att1P.p[i] = att1 + (size_t)i * DFEAT;
        att2P.p[i] = att2 + (size_t)i * DFEAT;
        b1P.p[i] = b1 + (size_t)i * DFEAT;
        b2P.p[i] = b2 + (size_t)i * DFEAT;
        st1P.p[i] = stats_all + (size_t)i * 512;
        st2P.p[i] = stats_all + (size_t)(3 + i) * 512;
        st1CP.p[i] = st1P.p[i];
        st2CP.p[i] = st2P.p[i];
        ssP.p[i] = ss_all + (size_t)i * 512;
        ssCP.p[i] = ssP.p[i];
        dumP.p[i] = xP.p[i];
        outP.p[i] = (float*)d_out + (size_t)nodeOff.a[i] * 2;
    }

    int maxNblk = (maxN + 255) / 256;
    int maxEblk = (maxE + 255) / 256;
    int maxMtile = (maxN + 127) / 128;
    int maxNwave = (maxN + 3) / 4;

    // one-time prep (R10/R12 structure)
    hipMemsetAsync(counts_all, 0, (size_t)Ntot * sizeof(int), stream);
    hipMemsetAsync(stats_all, 0, (size_t)6 * 512 * sizeof(float), stream);
    {
        WJobs jobs;
        for (int i = 0; i < 3; ++i) {
            jobs.src[i * 4 + 0] = Wl1 + (size_t)i * 128 * 256;
            jobs.dst[i * 4 + 0] = (unsigned short*)Bt1P.p[i];
            jobs.K[i * 4 + 0] = 128;
            jobs.src[i * 4 + 1] = Wr1 + (size_t)i * 128 * 256;
            jobs.dst[i * 4 + 1] = (unsigned short*)Bt1P.p[i] + (size_t)256 * 128;
            jobs.K[i * 4 + 1] = 128;
            jobs.src[i * 4 + 2] = Wl2 + (size_t)i * 256 * 256;
            jobs.dst[i * 4 + 2] = (unsigned short*)Bt2P.p[i];
            jobs.K[i * 4 + 2] = 256;
            jobs.src[i * 4 + 3] = Wr2 + (size_t)i * 256 * 256;
            jobs.dst[i * 4 + 3] = (unsigned short*)Bt2P.p[i] + (size_t)256 * 256;
            jobs.K[i * 4 + 3] = 256;
        }
        wcast_tr_k<<<dim3(4, 4, 12), 256, 0, stream>>>(jobs);
    }

    // ---- CSR build (all types) ----
    hist_all_k<<<dim3(maxEblk, 3), 256, 0, stream>>>(dstP, E3, counts_all, nodeOff);
    scan1_all_k<<<dim3(maxNblk, 3), 256, 0, stream>>>(counts_all, offs_all, bsums_all, N3, nodeOff, bOff);
    scan2_all_k<<<3, 256, 0, stream>>>(bsums_all, N3, bOff);
    scan3_all_k<<<dim3(maxNblk, 3), 256, 0, stream>>>(offs_all, counts_all, bsums_all, N3, E3, nodeOff, bOff);
    scatter_all_k<<<dim3(maxEblk, 3), 256, 0, stream>>>(srcP, dstP, E3, offs_all, counts_all, csr_all, nodeOff, edgeOff);

    // ---- layer 1 (A = x fp32, cast in staging) ----
    mfma_gemm_all_k<1><<<dim3(maxMtile, 4, 3), 256, 0, stream>>>(xP, Bt1P, dumP, CP, N3, 128);
    gat_gather_all_k<<<dim3(maxNwave, 1, 3), 256, 0, stream>>>(hlP, offsP, csrP, att1P, b1P, RbP, N3);
    bn_stats_all_k<<<dim3(512, 3), 256, 0, stream>>>(RbCP, st1P, N3);
    bn_finalize_all_k<<<3, 256, 0, stream>>>(st1CP, bn_g, bn_b, ssP, N3);

    // ---- layer 2 (A = Rb raw bf16 + fused BN+lrelu in staging) ----
    mfma_gemm_all_k<2><<<dim3(maxMtile, 4, 3), 256, 0, stream>>>(RbCP, Bt2P, ssCP, CP, N3, 256);
    gat_gather_all_k<<<dim3(maxNwave, 1, 3), 256, 0, stream>>>(hlP, offsP, csrP, att2P, b2P, RbP, N3);
    bn_stats_all_k<<<dim3(512, 3), 256, 0, stream>>>(RbCP, st2P, N3);

    // ---- fused BN + lrelu + classifier ----
    bn_cls_all_k<<<dim3(maxNwave, 3), 256, 0, stream>>>(RbCP, st2CP, bn_g, bn_b, cW, cb, outP, N3);
}